// Round 1
// baseline (973.328 us; speedup 1.0000x reference)
//
#include <hip/hip_runtime.h>
#include <cstdint>

#define N_VIS   8192
#define N_ASSOC 4096
#define N_MOTOR 1024
#define IN_DIM  4096
#define T_STEPS 16

__device__ __constant__ float DECAY_M_C = (float)(1.0 - 1.0/20.0);

// ---------------- coefficient table: C[s][r] = coefficient of outer(spk_r) in E_s ----------------
__global__ void coeff_kernel(const float* __restrict__ dop, unsigned* __restrict__ gate,
                             float* __restrict__ C) {
    if (blockIdx.x != 0 || threadIdx.x != 0) return;
    const float DE = (float)(1.0 - 1.0/500.0);
    unsigned g[T_STEPS];
    for (int t = 0; t < T_STEPS; ++t) {
        g[t] = (fabsf(dop[t]) > 0.1f) ? 1u : 0u;
        gate[t] = g[t];
    }
    for (int s = 0; s < T_STEPS; ++s)
        for (int r = 0; r < T_STEPS; ++r)
            C[s*16 + r] = 0.f;
    for (int s = 0; s < T_STEPS; ++s) {
        C[s*16 + s] = 1.f;
        for (int r = 0; r < s; ++r) {
            float c = C[(s-1)*16 + r];
            c = c * (g[s-1] ? 0.5f : 1.0f);   // post-step halving of step s-1 (exact)
            c = c * DE;                        // decay at start of step s
            C[s*16 + r] = c;
        }
    }
}

// ---------------- encoder + visual LIF: produce v_spk bitmasks for all 16 steps ----------------
__global__ __launch_bounds__(256) void encoder_kernel(
        const float* __restrict__ x, const float* __restrict__ noise,
        const float* __restrict__ W, const float* __restrict__ b,
        unsigned* __restrict__ vmask) {
    const int wave = threadIdx.x >> 6, lane = threadIdx.x & 63;
    const int i = blockIdx.x * 4 + wave;             // visual neuron
    const float4* Wr = (const float4*)(W + (size_t)i * IN_DIM);
    float acc[T_STEPS];
#pragma unroll
    for (int t = 0; t < T_STEPS; ++t) acc[t] = 0.f;
    for (int m = 0; m < 16; ++m) {
        int k4 = m * 64 + lane;                      // float4 index within row (0..1023)
        float4 wv = Wr[k4];
#pragma unroll
        for (int t = 0; t < T_STEPS; ++t) {
            float4 xv = ((const float4*)(x + t * IN_DIM))[k4];
            acc[t] += wv.x * xv.x + wv.y * xv.y + wv.z * xv.z + wv.w * xv.w;
        }
    }
#pragma unroll
    for (int t = 0; t < T_STEPS; ++t) {
        float a = acc[t];
        for (int off = 32; off; off >>= 1) a += __shfl_xor(a, off, 64);
        acc[t] = a;
    }
    if (lane == 0) {
        float bb = b[i];
        float v = 0.f;
        unsigned msk = 0;
        for (int t = 0; t < T_STEPS; ++t) {
            float logit = acc[t] + bb;
            float rate = 1.0f / (1.0f + expf(-logit));
            float u = noise[t * N_VIS + i];
            float ins = (u < rate * 0.3f) ? 1.0f : 0.0f;
            v = v * DECAY_M_C + ins;
            if (v > 1.0f) { msk |= (1u << t); v = 0.f; }
        }
        vmask[i] = msk;
    }
}

// ---------------- fused plasticity-update(t_upd) + matvec(t_mv) + LIF epilogue ----------------
__device__ __forceinline__ float updw(float w, unsigned am, float d, const float* lut) {
    float S = lut[am & 255] + lut[256 + (am >> 8)];
    float e = 0.01f * S;                       // eligibility value
    float delta = d * e * 0.1f;
    delta = fminf(fmaxf(delta, -0.01f), 0.01f);
    return fminf(fmaxf(w + delta, 0.0f), 1.0f);
}

__global__ __launch_bounds__(256) void fused_step(
        const float* __restrict__ Wsrc, float* __restrict__ Wdst,
        const unsigned* __restrict__ colmask, unsigned* __restrict__ rowmask,
        const float* __restrict__ dop, const unsigned* __restrict__ gate,
        const float* __restrict__ C, float* __restrict__ Vstate,
        float* __restrict__ outp,
        int L, int t_upd, int t_mv, int force_write) {
    const int j = blockIdx.x;
    const int tid = threadIdx.x;
    __shared__ float lut[512];
    __shared__ float red[4];

    const bool upd_phase = (t_upd >= 0);
    float d = 0.f;
    unsigned g = 0;
    if (upd_phase) {
        g = gate[t_upd];
        d = dop[t_upd];
        const float* Cr = C + t_upd * 16;
        for (int n = tid; n < 512; n += 256) {
            int half = n >> 8, idx = n & 255;
            float s = 0.f;
#pragma unroll
            for (int bb = 0; bb < 8; ++bb)
                if ((idx >> bb) & 1) s += Cr[half * 8 + bb];
            lut[n] = s;
        }
        __syncthreads();
    }
    const bool do_upd = upd_phase && (g != 0);
    const bool do_write = upd_phase && (g != 0 || force_write != 0);

    const unsigned rm = rowmask[j];
    const size_t base = (size_t)j * L;
    const float4* Ws4 = (const float4*)(Wsrc + base);
    float4* Wd4 = (float4*)(Wdst + base);
    const uint4* cm4 = (const uint4*)colmask;

    float acc = 0.f;
    const int n4 = L >> 2;
    for (int i4 = tid; i4 < n4; i4 += 256) {
        float4 w = Ws4[i4];
        uint4 vm = cm4[i4];
        if (do_upd) {
            w.x = updw(w.x, vm.x & rm, d, lut);
            w.y = updw(w.y, vm.y & rm, d, lut);
            w.z = updw(w.z, vm.z & rm, d, lut);
            w.w = updw(w.w, vm.w & rm, d, lut);
        }
        if (do_write) Wd4[i4] = w;
        acc += (((vm.x >> t_mv) & 1) ? w.x : 0.f);
        acc += (((vm.y >> t_mv) & 1) ? w.y : 0.f);
        acc += (((vm.z >> t_mv) & 1) ? w.z : 0.f);
        acc += (((vm.w >> t_mv) & 1) ? w.w : 0.f);
    }
    for (int off = 32; off; off >>= 1) acc += __shfl_down(acc, off, 64);
    const int lane = tid & 63, wv = tid >> 6;
    if (lane == 0) red[wv] = acc;
    __syncthreads();
    if (tid == 0) {
        float total = red[0] + red[1] + red[2] + red[3];
        float v = Vstate[j] * DECAY_M_C + total * 0.1f;
        int s = (v > 1.0f) ? 1 : 0;
        if (s) rowmask[j] = rm | (1u << t_mv);
        Vstate[j] = s ? 0.f : v;
        if (outp) outp[t_mv * N_MOTOR + j] = s ? 1.0f : 0.0f;
    }
}

extern "C" void kernel_launch(void* const* d_in, const int* in_sizes, int n_in,
                              void* d_out, int out_size, void* d_ws, size_t ws_size,
                              hipStream_t stream) {
    const float* x     = (const float*)d_in[0];   // [16, 4096]
    const float* noise = (const float*)d_in[1];   // [16, 8192]
    const float* dop   = (const float*)d_in[2];   // [16]
    const float* W_enc = (const float*)d_in[3];   // [8192, 4096]
    const float* b_enc = (const float*)d_in[4];   // [8192]
    const float* W_va  = (const float*)d_in[5];   // [4096, 8192]
    const float* W_am  = (const float*)d_in[6];   // [1024, 4096]
    float* out = (float*)d_out;                   // [16, 1024] f32

    char* ws = (char*)d_ws;
    size_t off = 0;
    float*    wsVA  = (float*)(ws + off); off += (size_t)N_ASSOC * N_VIS * 4;
    float*    wsAM  = (float*)(ws + off); off += (size_t)N_MOTOR * N_ASSOC * 4;
    unsigned* vmask = (unsigned*)(ws + off); off += (size_t)N_VIS * 4;
    unsigned* amask = (unsigned*)(ws + off); off += (size_t)N_ASSOC * 4;
    unsigned* mmask = (unsigned*)(ws + off); off += (size_t)N_MOTOR * 4;
    float*    vA    = (float*)(ws + off); off += (size_t)N_ASSOC * 4;
    float*    vM    = (float*)(ws + off); off += (size_t)N_MOTOR * 4;
    float*    C     = (float*)(ws + off); off += 16 * 16 * 4;
    unsigned* gate  = (unsigned*)(ws + off); off += 16 * 4;
    (void)ws_size; (void)in_sizes; (void)n_in; (void)out_size;

    hipMemsetAsync(amask, 0, N_ASSOC * 4, stream);
    hipMemsetAsync(mmask, 0, N_MOTOR * 4, stream);
    hipMemsetAsync(vA,    0, N_ASSOC * 4, stream);
    hipMemsetAsync(vM,    0, N_MOTOR * 4, stream);

    coeff_kernel<<<1, 1, 0, stream>>>(dop, gate, C);
    encoder_kernel<<<N_VIS / 4, 256, 0, stream>>>(x, noise, W_enc, b_enc, vmask);

    // step 0: pure matvecs on the pristine input weights
    fused_step<<<N_ASSOC, 256, 0, stream>>>(W_va, wsVA, vmask, amask, dop, gate, C, vA,
                                            nullptr, N_VIS, -1, 0, 0);
    fused_step<<<N_MOTOR, 256, 0, stream>>>(W_am, wsAM, amask, mmask, dop, gate, C, vM,
                                            out, N_ASSOC, -1, 0, 0);
    for (int t = 1; t < T_STEPS; ++t) {
        const float* srcVA = (t == 1) ? W_va : wsVA;
        const float* srcAM = (t == 1) ? W_am : wsAM;
        int force = (t == 1) ? 1 : 0;
        // apply step t-1 plasticity to W, then matvec with spikes of step t, then LIF(t)
        fused_step<<<N_ASSOC, 256, 0, stream>>>(srcVA, wsVA, vmask, amask, dop, gate, C, vA,
                                                nullptr, N_VIS, t - 1, t, force);
        fused_step<<<N_MOTOR, 256, 0, stream>>>(srcAM, wsAM, amask, mmask, dop, gate, C, vM,
                                                out, N_ASSOC, t - 1, t, force);
    }
}

// Round 2
// 257.990 us; speedup vs baseline: 3.7727x; 3.7727x over previous
//
#include <hip/hip_runtime.h>
#include <cstdint>

#define N_VIS   8192
#define N_ASSOC 4096
#define N_MOTOR 1024
#define IN_DIM  4096
#define T_STEPS 16

// ---------------- encoder + visual LIF: 4 rows per wave, 16 rows per block ----------------
__global__ __launch_bounds__(256) void encoder_kernel(
        const float* __restrict__ x, const float* __restrict__ noise,
        const float* __restrict__ W, const float* __restrict__ b,
        unsigned* __restrict__ vmask) {
    const int wave = threadIdx.x >> 6, lane = threadIdx.x & 63;
    const int i0 = (blockIdx.x * 4 + wave) * 4;      // first of this wave's 4 rows
    const float4* r0 = (const float4*)(W + (size_t)(i0 + 0) * IN_DIM);
    const float4* r1 = (const float4*)(W + (size_t)(i0 + 1) * IN_DIM);
    const float4* r2 = (const float4*)(W + (size_t)(i0 + 2) * IN_DIM);
    const float4* r3 = (const float4*)(W + (size_t)(i0 + 3) * IN_DIM);

    float acc0[T_STEPS], acc1[T_STEPS], acc2[T_STEPS], acc3[T_STEPS];
#pragma unroll
    for (int t = 0; t < T_STEPS; ++t) { acc0[t]=0.f; acc1[t]=0.f; acc2[t]=0.f; acc3[t]=0.f; }

    for (int m = 0; m < 16; ++m) {
        const int k4 = m * 64 + lane;                // float4 index within row
        float4 w0 = r0[k4], w1 = r1[k4], w2 = r2[k4], w3 = r3[k4];
#pragma unroll
        for (int t = 0; t < T_STEPS; ++t) {
            float4 xv = ((const float4*)(x + t * IN_DIM))[k4];
            acc0[t] += w0.x*xv.x + w0.y*xv.y + w0.z*xv.z + w0.w*xv.w;
            acc1[t] += w1.x*xv.x + w1.y*xv.y + w1.z*xv.z + w1.w*xv.w;
            acc2[t] += w2.x*xv.x + w2.y*xv.y + w2.z*xv.z + w2.w*xv.w;
            acc3[t] += w3.x*xv.x + w3.y*xv.y + w3.z*xv.z + w3.w*xv.w;
        }
    }
#pragma unroll
    for (int t = 0; t < T_STEPS; ++t) {
        float a;
        a = acc0[t]; for (int off = 32; off; off >>= 1) a += __shfl_xor(a, off, 64); acc0[t] = a;
        a = acc1[t]; for (int off = 32; off; off >>= 1) a += __shfl_xor(a, off, 64); acc1[t] = a;
        a = acc2[t]; for (int off = 32; off; off >>= 1) a += __shfl_xor(a, off, 64); acc2[t] = a;
        a = acc3[t]; for (int off = 32; off; off >>= 1) a += __shfl_xor(a, off, 64); acc3[t] = a;
    }
    if (lane == 0) {
        auto do_row = [&](int i, const float (&a)[T_STEPS]) {
            float bb = b[i];
            float v = 0.f;
            unsigned msk = 0;
#pragma unroll
            for (int t = 0; t < T_STEPS; ++t) {
                float logit = a[t] + bb;
                float rate = 1.0f / (1.0f + expf(-logit));
                float u = noise[t * N_VIS + i];
                float ins = (u < rate * 0.3f) ? 1.0f : 0.0f;
                v = v * 0.95f + ins;
                if (v > 1.0f) { msk |= (1u << t); v = 0.f; }
            }
            vmask[i] = msk;
        };
        do_row(i0 + 0, acc0);
        do_row(i0 + 1, acc1);
        do_row(i0 + 2, acc2);
        do_row(i0 + 3, acc3);
    }
}

// ---------------- one block per row: all 16 steps in registers (W row + eligibility row) -----
// NC = float4 chunks per thread (row length / 1024).
template<int NC>
__global__ __launch_bounds__(256) void snn_layer_kernel(
        const float* __restrict__ W0, const unsigned* __restrict__ colmask,
        const float* __restrict__ dop, unsigned* __restrict__ rowmask_out,
        float* __restrict__ outp, int out_stride) {
    const int j = blockIdx.x;
    const int tid = threadIdx.x;
    const int lane = tid & 63, wv_id = tid >> 6;
    __shared__ float sd[T_STEPS];
    __shared__ float red[4];
    __shared__ float sspk;

    if (tid < T_STEPS) sd[tid] = dop[tid];

    const float4* Wr = (const float4*)(W0 + (size_t)j * (NC * 1024));
    const uint4*  cm = (const uint4*)colmask;

    float    w[NC * 4];
    float    e[NC * 4];
    unsigned vmp[NC * 2];          // packed: low 16 bits = comp {x,z}, high 16 = comp {y,w}
#pragma unroll
    for (int k = 0; k < NC; ++k) {
        float4 wv = Wr[tid + k * 256];
        uint4  mv = cm[tid + k * 256];
        w[k*4+0] = wv.x; w[k*4+1] = wv.y; w[k*4+2] = wv.z; w[k*4+3] = wv.w;
        vmp[k*2+0] = mv.x | (mv.y << 16);
        vmp[k*2+1] = mv.z | (mv.w << 16);
        e[k*4+0] = 0.f; e[k*4+1] = 0.f; e[k*4+2] = 0.f; e[k*4+3] = 0.f;
    }
    __syncthreads();

    float    decay_next = 0.998f;      // folds the exact x0.5 halving of gated steps
    float    vmem = 0.f;               // valid on tid 0 only
    unsigned rmask = 0;                // valid on tid 0 only

    for (int t = 0; t < T_STEPS; ++t) {
        const unsigned mlo = 1u << t;
        const unsigned mhi = 65536u << t;

        // ---- matvec with current W against column-spikes of step t ----
        float acc = 0.f;
#pragma unroll
        for (int k = 0; k < NC; ++k) {
            acc += (vmp[k*2+0] & mlo) ? w[k*4+0] : 0.f;
            acc += (vmp[k*2+0] & mhi) ? w[k*4+1] : 0.f;
            acc += (vmp[k*2+1] & mlo) ? w[k*4+2] : 0.f;
            acc += (vmp[k*2+1] & mhi) ? w[k*4+3] : 0.f;
        }
        for (int off = 32; off; off >>= 1) acc += __shfl_down(acc, off, 64);
        if (lane == 0) red[wv_id] = acc;
        __syncthreads();
        if (tid == 0) {
            float total = red[0] + red[1] + red[2] + red[3];
            vmem = vmem * 0.95f + total * 0.1f;
            bool s = vmem > 1.0f;
            if (s) { vmem = 0.f; rmask |= (1u << t); }
            sspk = s ? 1.0f : 0.0f;
            if (outp) outp[t * out_stride + j] = s ? 1.0f : 0.0f;
        }
        __syncthreads();

        // ---- eligibility + gated plastic update ----
        const float abit  = sspk;                // 0 or 1 (row spike this step)
        const float d     = sd[t];
        const bool  g     = fabsf(d) > 0.1f;
        const float s_inc = abit * 0.01f;        // exact: 0.01 or 0
        const float dm    = decay_next;
#pragma unroll
        for (int k = 0; k < NC; ++k) {
#pragma unroll
            for (int c = 0; c < 4; ++c) {
                const int el = k * 4 + c;
                const unsigned bit = vmp[k*2 + (c >> 1)] & ((c & 1) ? mhi : mlo);
                float ev = e[el] * dm + (bit ? s_inc : 0.f);
                e[el] = ev;
                if (g) {
                    float delta = (d * ev) * 0.1f;
                    delta = fminf(fmaxf(delta, -0.01f), 0.01f);
                    w[el] = fminf(fmaxf(w[el] + delta, 0.f), 1.f);
                }
            }
        }
        decay_next = g ? (0.998f * 0.5f) : 0.998f;
    }
    if (tid == 0 && rowmask_out) rowmask_out[j] = rmask;
}

extern "C" void kernel_launch(void* const* d_in, const int* in_sizes, int n_in,
                              void* d_out, int out_size, void* d_ws, size_t ws_size,
                              hipStream_t stream) {
    const float* x     = (const float*)d_in[0];   // [16, 4096]
    const float* noise = (const float*)d_in[1];   // [16, 8192]
    const float* dop   = (const float*)d_in[2];   // [16]
    const float* W_enc = (const float*)d_in[3];   // [8192, 4096]
    const float* b_enc = (const float*)d_in[4];   // [8192]
    const float* W_va  = (const float*)d_in[5];   // [4096, 8192]
    const float* W_am  = (const float*)d_in[6];   // [1024, 4096]
    float* out = (float*)d_out;                   // [16, 1024] f32
    (void)in_sizes; (void)n_in; (void)out_size; (void)ws_size;

    unsigned* vmask = (unsigned*)d_ws;            // [8192]
    unsigned* amask = vmask + N_VIS;              // [4096]

    encoder_kernel<<<N_VIS / 16, 256, 0, stream>>>(x, noise, W_enc, b_enc, vmask);
    snn_layer_kernel<8><<<N_ASSOC, 256, 0, stream>>>(W_va, vmask, dop, amask, nullptr, 0);
    snn_layer_kernel<4><<<N_MOTOR, 256, 0, stream>>>(W_am, amask, dop, nullptr, out, N_MOTOR);
}